// Round 18
// baseline (37.078 us; speedup 1.0000x reference)
//
#include <hip/hip_runtime.h>

// VQ-VAE vector quantizer, MI355X. 2 kernels. FP8 e4m3 operands + PER-BLOCK
// CHUNK-ORDER ROTATION: block bid walks Bg chunks in order (t + bid%17) % 17,
// spreading the 256 blocks' concurrent L2 reads across all 34 planes instead
// of one shared 16 KB window (tests the L2 same-line-contention hypothesis).
//  K1 vq_prep : emb f32 -> Bg fp8 [34 planes][1024 codes][8B]; planes 0-31 =
//               e*512; planes 32,33 = splat(-256*enorm); zero ctrl.
//  K2 vq_main : 256 blocks x 512 thr; 64 rows x 1024 codes per block.
//    K loop: 17 chunks K=16 (rotated order), 3-buffer ring, counted
//            vmcnt(4/2/0) + raw barriers, setprio MFMA cluster.
//    epilogue: swapped-operand lane-local argmax -> idx; gather emb -> out;
//              fixed-point u64 loss.
// z: [16,256,32,32] f32, emb_w: [1024,256] f32
// out: z_q f32 (4194304) ++ loss scalar (1 float)

#define K_CODES 1024
#define D_DIM   256
#define ZQ_SIZE 4194304
#define NBLK    256

typedef unsigned long long u64;
typedef float f32x16 __attribute__((ext_vector_type(16)));

struct Ctrl { unsigned done; unsigned pad; u64 lsum; };

// float -> OCP e4m3fn, RNE (clamp at 448; crude-but-adequate subnormals)
__device__ __forceinline__ unsigned f2e4m3(float x) {
    unsigned u = __float_as_uint(x);
    unsigned s = (u >> 24) & 0x80u;
    unsigned au = u & 0x7fffffffu;
    if (au >= 0x43E00000u) return s | 0x7Eu;          // |x| >= 448 -> max finite
    if (au < 0x3C800000u) {                           // |x| < 2^-6 -> subnormal
        float ax = __uint_as_float(au);
        unsigned n = (unsigned)(ax * 512.0f + 0.5f);  // steps of 2^-9
        return s | (n >= 8u ? 0x08u : n);
    }
    unsigned e = au >> 23, m = au & 0x7fffffu;
    m += 0x7FFFFu + ((m >> 20) & 1u);                 // RNE at mantissa bit 20
    if (m >> 23) { m = 0; e += 1u; }
    if (e >= 136u) return s | 0x7Eu;
    return s | ((e - 120u) << 3) | (m >> 20);
}

__device__ __forceinline__ void gload_lds16(const void* g, void* l) {
    __builtin_amdgcn_global_load_lds(
        (const __attribute__((address_space(1))) void*)g,
        (__attribute__((address_space(3))) void*)l, 16, 0, 0);
}

// ---------------- K1: emb -> Bg fp8 (34 planes) ; zero ctrl ----------------
__global__ __launch_bounds__(512) void vq_prep(
        const float* __restrict__ emb, unsigned char* __restrict__ Bg,
        Ctrl* __restrict__ ctrl) {
    const int gi = blockIdx.x * 512 + threadIdx.x;   // [0, 32768)
    const int k = gi >> 5, g = gi & 31;
    const float4 v0 = *(const float4*)(emb + k * D_DIM + g * 8);
    const float4 v1 = *(const float4*)(emb + k * D_DIM + g * 8 + 4);
    const float vv[8] = { v0.x, v0.y, v0.z, v0.w, v1.x, v1.y, v1.z, v1.w };
    float s = 0.f;
    u64 pk = 0ull;
#pragma unroll
    for (int j = 0; j < 8; ++j) {
        s += vv[j] * vv[j];
        pk |= (u64)f2e4m3(vv[j] * 512.0f) << (8 * j);   // store e * 512
    }
    *(u64*)(Bg + ((size_t)g * K_CODES + k) * 8) = pk;
#pragma unroll
    for (int off = 16; off >= 1; off >>= 1) s += __shfl_xor(s, off);   // enorm, all lanes
    if (g < 2) {   // planes 32,33: splat(-256*enorm); A=1/16 chunk: 16*(1/16)*v = v
        u64 e8 = (u64)f2e4m3(-256.0f * s) * 0x0101010101010101ull;
        *(u64*)(Bg + ((size_t)(32 + g) * K_CODES + k) * 8) = e8;
    }
    if (gi == 0) { ctrl->done = 0u; ctrl->lsum = 0ull; }
}

// ---------------- K2: main ----------------
// LDS map (bytes):
//   As   [     0, 16384)  [32 planes][64 rows][8B] fp8 (K loop; dead after)
//   Bs   [ 16384, 65536)  3 x 16384 ring (K loop; dead after)
//   znp  [ 65536, 67584)  [64][8] f32 (prologue)
//   pmin [ 65536, 67584)  [64][4] u64 (epilogue; aliases znp)
//   znL  [ 67584, 67840)  [64] f32
//   idxL [ 67840, 68096)  [64] i32
//   et   [     0, 66560)  [64][260] f32 (output phase; aliases As+Bs)
__global__ __launch_bounds__(512, 2) void vq_main(
        const float* __restrict__ z, const float* __restrict__ emb,
        const unsigned char* __restrict__ Bg,
        float* __restrict__ out, float* __restrict__ loss, Ctrl* __restrict__ ctrl) {
    __shared__ __align__(16) char smem[68096];
    unsigned char* As = (unsigned char*)smem;
    unsigned char* Bs = (unsigned char*)(smem + 16384);
    float*    znp  = (float*)(smem + 65536);
    u64*      pmin = (u64*)(smem + 65536);
    float*    znL  = (float*)(smem + 67584);
    int*      idxL = (int*)(smem + 67840);
    float*    et   = (float*)smem;

    const int bid = blockIdx.x, tid = threadIdx.x;
    const int b = bid >> 4;
    const int hw0 = (bid & 15) * 64;
    const int w = tid >> 6, l = tid & 63;
    const int wm = w >> 2, wn = w & 3;               // 2 row-groups x 4 code-groups
    const int lane31 = l & 31, hi = l >> 5;

    // per-block rotated chunk order: ci(t) = (t + bid) mod 17
    const int off17 = bid % 17;
    auto ci = [&](int t) { int c = t + off17; return c >= 17 ? c - 17 : c; };

    // stage chunk c (16 KB = planes {2c,2c+1}, contiguous in Bg): 2 loads/thread
    auto stage = [&](int sbuf, int c) {
#pragma unroll
        for (int qq = 0; qq < 2; ++qq) {
            int g = qq * 512 + tid;                  // [0,1024) 16B granules
            gload_lds16(Bg + (size_t)c * 16384 + (size_t)g * 16,
                        Bs + (size_t)sbuf * 16384 + (size_t)g * 16);
        }
    };

    stage(0, ci(0));
    stage(1, ci(1));   // drained by the prologue's __syncthreads

    // ---- prologue: z -> As fp8 (coalesced 256B-segment loads) + znorm -> znL ----
    {
        const float* zb = z + (size_t)b * (D_DIM * 1024) + hw0;
        const int hw = tid & 63, gs = tid >> 6;      // gs in [0,8)
        float zn = 0.f;
#pragma unroll
        for (int gi = 0; gi < 4; ++gi) {
            const int g = gs * 4 + gi;               // granule plane [0,32)
            float v[8];
            u64 pk = 0ull;
#pragma unroll
            for (int j = 0; j < 8; ++j) v[j] = zb[(size_t)(g * 8 + j) * 1024 + hw];
#pragma unroll
            for (int j = 0; j < 8; ++j) {
                zn += v[j] * v[j];
                pk |= (u64)f2e4m3(v[j]) << (8 * j);   // z unscaled
            }
            *(u64*)(As + ((size_t)g * 64 + hw) * 8) = pk;
        }
        znp[hw * 8 + gs] = zn;
        __syncthreads();                             // As + znp ready; drains stage 0,1
        if (tid < 64) {
            float s = 0.f;
#pragma unroll
            for (int g = 0; g < 8; ++g) s += znp[tid * 8 + g];
            znL[tid] = s;
        }
        __syncthreads();                             // znp reads done; znL ready
    }

    // ---- K loop: 17 chunks in rotated order, 3-ring counted-vmcnt pipeline ----
    f32x16 acc[8];
#pragma unroll
    for (int cf = 0; cf < 8; ++cf)
#pragma unroll
        for (int r = 0; r < 16; ++r) acc[cf][r] = 0.f;

    // CI==16 is the enorm chunk: A = splat fp8(1/16); else A from As plane pair
#define COMPUTE(BUF, CI) do {                                                   \
        const unsigned char* Bp = Bs + (size_t)(BUF) * 16384 + hi * 8192 +      \
                                  (size_t)(wn * 256) * 8;                       \
        long a;                                                                 \
        if ((CI) < 16) a = *(const long*)(As + ((size_t)((CI) * 2 + hi) * 64    \
                                                + wm * 32 + lane31) * 8);       \
        else a = 0x1818181818181818L;  /* 8 x fp8(1/16) */                      \
        __builtin_amdgcn_s_setprio(1);                                          \
        _Pragma("unroll")                                                       \
        for (int cf = 0; cf < 8; ++cf) {                                        \
            const long bf = *(const long*)(Bp + (size_t)(cf * 32 + lane31) * 8); \
            acc[cf] = __builtin_amdgcn_mfma_f32_32x32x16_fp8_fp8(bf, a, acc[cf], 0, 0, 0); \
        }                                                                       \
        __builtin_amdgcn_s_setprio(0);                                          \
    } while (0)

    int bcur = 0, bnxt = 2;
    for (int t = 0; t < 15; ++t) {
        stage(bnxt, ci(t + 2));                      // slot (t+2)%3: last read iter t-1
        asm volatile("s_waitcnt vmcnt(4)" ::: "memory");   // chunk t done; t+1,t+2 fly
        __builtin_amdgcn_s_barrier();
        __builtin_amdgcn_sched_barrier(0);
        COMPUTE(bcur, ci(t));
        __builtin_amdgcn_s_barrier();                // all reads of chunk t done
        bcur = (bcur == 2) ? 0 : bcur + 1;
        bnxt = (bnxt == 2) ? 0 : bnxt + 1;
    }
    asm volatile("s_waitcnt vmcnt(2)" ::: "memory");
    __builtin_amdgcn_s_barrier();
    __builtin_amdgcn_sched_barrier(0);
    COMPUTE(bcur, ci(15));
    __builtin_amdgcn_s_barrier();
    bcur = (bcur == 2) ? 0 : bcur + 1;
    asm volatile("s_waitcnt vmcnt(0)" ::: "memory");
    __builtin_amdgcn_s_barrier();
    __builtin_amdgcn_sched_barrier(0);
    COMPUTE(bcur, ci(16));
#undef COMPUTE

    // ---- epilogue: lane-local argmax over 128 codes (sc = 512 z.e - 256 enorm) ----
    {
        float m = acc[0][0];
#pragma unroll
        for (int cf = 0; cf < 8; ++cf)
#pragma unroll
            for (int r = 0; r < 16; ++r) m = fmaxf(m, acc[cf][r]);
        unsigned cc = 0xffffffffu;
#pragma unroll
        for (int cf = 0; cf < 8; ++cf)
#pragma unroll
            for (int r = 0; r < 16; ++r) {
                const unsigned cst = (unsigned)(cf * 32 + (r & 3) + 8 * (r >> 2));
                if (acc[cf][r] == m) cc = cst < cc ? cst : cc;
            }
        unsigned code = cc + (unsigned)(wn * 256 + 4 * hi);
        const float om = __shfl_xor(m, 32);
        const unsigned oc = __shfl_xor(code, 32);
        if (om > m || (om == m && oc < code)) { m = om; code = oc; }
        unsigned sb = __float_as_uint(m);
        unsigned s = sb ^ (unsigned)(((int)sb >> 31) | 0x80000000);
        u64 key = ((u64)(~s) << 32) | code;          // min key = max score, tie->min code
        __builtin_amdgcn_s_barrier();                // As/Bs phase done (pmin aliases znp)
        if (l < 32) pmin[(wm * 32 + lane31) * 4 + wn] = key;
    }
    __syncthreads();

    // ---- final per-row min across 4 code-waves -> idx + loss ----
    if (tid < 64) {
        u64 b0 = pmin[tid * 4], b1 = pmin[tid * 4 + 1];
        u64 b2 = pmin[tid * 4 + 2], b3 = pmin[tid * 4 + 3];
        u64 m01 = b0 < b1 ? b0 : b1;
        u64 m23 = b2 < b3 ? b2 : b3;
        u64 best = m01 < m23 ? m01 : m23;
        idxL[tid] = (int)(best & 1023u);
        unsigned us = ~(unsigned)(best >> 32);
        unsigned fb = (us & 0x80000000u) ? (us ^ 0x80000000u) : ~us;
        float sc = __uint_as_float(fb);              // max(512 z.e - 256 enorm)
        float lp = znL[tid] - sc * (1.0f / 256.0f);  // ||z||^2 - 2 z.e + enorm
#pragma unroll
        for (int off = 32; off >= 1; off >>= 1) lp += __shfl_xor(lp, off);
        if (tid == 0) {
            u64 fix = (u64)(long long)((double)lp * 1048576.0);
            atomicAdd(&ctrl->lsum, fix);
            __threadfence();
            unsigned old = atomicAdd(&ctrl->done, 1u);
            if (old == (NBLK - 1)) {
                __threadfence();
                u64 tot = atomicAdd(&ctrl->lsum, 0ull);
                loss[0] = (float)((double)tot * (1.25 / (1048576.0 * 4194304.0)));
            }
        }
    }
    __syncthreads();   // idxL ready; As/Bs/pmin dead -> et may overwrite

    // ---- gather emb rows -> et[local row] (1 KB coalesced per wave pass) ----
#pragma unroll
    for (int jj = 0; jj < 8; ++jj) {
        int j = jj * 512 + tid;                      // row = j>>6 in [0,64), gr = j&63
        int mrow = j >> 6, gr = j & 63;
        float4 v = *(const float4*)(emb + (size_t)idxL[mrow] * D_DIM + gr * 4);
        *(float4*)(et + mrow * 260 + gr * 4) = v;
    }
    __syncthreads();

    // ---- out[b][d][hw0+hw] = et[hw][d] ----
    const int hw4 = (tid & 15) * 4;
    const int dr = tid >> 4;                         // 0..31
#pragma unroll
    for (int it = 0; it < 8; ++it) {
        const int d = it * 32 + dr;
        float4 qv;
        qv.x = et[(hw4 + 0) * 260 + d];
        qv.y = et[(hw4 + 1) * 260 + d];
        qv.z = et[(hw4 + 2) * 260 + d];
        qv.w = et[(hw4 + 3) * 260 + d];
        *(float4*)(out + ((size_t)(b * 256 + d)) * 1024 + hw0 + hw4) = qv;
    }
}

extern "C" void kernel_launch(void* const* d_in, const int* in_sizes, int n_in,
                              void* d_out, int out_size, void* d_ws, size_t ws_size,
                              hipStream_t stream) {
    const float* z   = (const float*)d_in[0];
    const float* emb = (const float*)d_in[1];
    float* out  = (float*)d_out;
    float* loss = out + ZQ_SIZE;

    char* ws = (char*)d_ws;
    unsigned char* Bg = (unsigned char*)(ws);   //  278,528 B  [34][1024] 8B granules
    Ctrl* ctrl = (Ctrl*)(ws + 278528);          //       16 B

    vq_prep<<<64, 512, 0, stream>>>(emb, Bg, ctrl);
    vq_main<<<NBLK, 512, 0, stream>>>(z, emb, Bg, out, loss, ctrl);
}

// Round 19
// 35.019 us; speedup vs baseline: 1.0588x; 1.0588x over previous
//
#include <hip/hip_runtime.h>

// VQ-VAE vector quantizer, MI355X. 2 kernels (prep-offload variant of R11-best).
//  K1 vq_prep (320 blocks x 512 thr):
//    bid<256 : z -> Ag bf16 granule-planar [32][16384][8] + znorm -> znG (global)
//    bid>=256: emb -> Bg bf16 [34 planes][1024][8]; planes 32,33 = splat(-enorm/32);
//              zero ctrl.
//  K2 vq_main (256 blocks x 512 thr, R11 K-loop/epilogue verbatim):
//    prologue: stage B chunks 0,1 + As (all via global_load_lds) + znL; ONE barrier.
//    K loop:   17 chunks K=16, 3-buffer ring, counted vmcnt(8/4/0) + raw barriers,
//              setprio MFMA cluster.
//    epilogue: swapped-operand lane-local argmax -> idx; gather emb -> out;
//              fixed-point u64 loss.
// z: [16,256,32,32] f32, emb_w: [1024,256] f32
// out: z_q f32 (4194304) ++ loss scalar (1 float)

#define K_CODES 1024
#define D_DIM   256
#define N_VEC   16384
#define ZQ_SIZE 4194304
#define NBLK    256

typedef unsigned short ushort_t;
typedef unsigned long long u64;
typedef short bf16x8 __attribute__((ext_vector_type(8)));
typedef float f32x16 __attribute__((ext_vector_type(16)));

struct Ctrl { unsigned done; unsigned pad; u64 lsum; };

__device__ __forceinline__ ushort_t f2bf(float x) {
    unsigned int b = __float_as_uint(x);
    b += 0x7fffu + ((b >> 16) & 1u);   // RNE
    return (ushort_t)(b >> 16);
}

__device__ __forceinline__ void gload_lds16(const void* g, void* l) {
    __builtin_amdgcn_global_load_lds(
        (const __attribute__((address_space(1))) void*)g,
        (__attribute__((address_space(3))) void*)l, 16, 0, 0);
}

// ---------------- K1: all prep ----------------
__global__ __launch_bounds__(512) void vq_prep(
        const float* __restrict__ z, const float* __restrict__ emb,
        ushort_t* __restrict__ Ag, float* __restrict__ znG,
        ushort_t* __restrict__ Bg, Ctrl* __restrict__ ctrl) {
    __shared__ float znp[512];
    const int bid = blockIdx.x, tid = threadIdx.x;

    if (bid < 256) {
        // z rows n = bid*64 .. +64, all 256 d -> Ag planes + znorm
        const int b = bid >> 4;
        const int hw0 = (bid & 15) * 64;
        const float* zb = z + (size_t)b * (D_DIM * 1024) + hw0;
        const int hw = tid & 63, gs = tid >> 6;      // gs in [0,8)
        const int n = bid * 64 + hw;
        float zn = 0.f;
#pragma unroll
        for (int gi = 0; gi < 4; ++gi) {
            const int g = gs * 4 + gi;               // granule plane [0,32)
            float v[8]; ushort_t o[8];
#pragma unroll
            for (int j = 0; j < 8; ++j) v[j] = zb[(size_t)(g * 8 + j) * 1024 + hw];
#pragma unroll
            for (int j = 0; j < 8; ++j) { zn += v[j] * v[j]; o[j] = f2bf(v[j]); }
            *(bf16x8*)(Ag + ((size_t)g * N_VEC + n) * 8) = *(bf16x8*)o;  // 1KB/wave
        }
        znp[hw * 8 + gs] = zn;
        __syncthreads();
        if (tid < 64) {
            float s = 0.f;
#pragma unroll
            for (int g = 0; g < 8; ++g) s += znp[tid * 8 + g];
            znG[bid * 64 + tid] = s;
        }
    } else {
        // emb -> Bg (34 planes); zero ctrl
        const int gi = (bid - 256) * 512 + tid;      // [0, 32768)
        const int k = gi >> 5, g = gi & 31;
        const float4 v0 = *(const float4*)(emb + k * D_DIM + g * 8);
        const float4 v1 = *(const float4*)(emb + k * D_DIM + g * 8 + 4);
        ushort_t o[8];
        o[0] = f2bf(v0.x); o[1] = f2bf(v0.y); o[2] = f2bf(v0.z); o[3] = f2bf(v0.w);
        o[4] = f2bf(v1.x); o[5] = f2bf(v1.y); o[6] = f2bf(v1.z); o[7] = f2bf(v1.w);
        *(bf16x8*)(Bg + ((size_t)g * K_CODES + k) * 8) = *(bf16x8*)o;
        float s = v0.x * v0.x + v0.y * v0.y + v0.z * v0.z + v0.w * v0.w
                + v1.x * v1.x + v1.y * v1.y + v1.z * v1.z + v1.w * v1.w;
#pragma unroll
        for (int off = 16; off >= 1; off >>= 1) s += __shfl_xor(s, off);
        if (g < 2) {   // planes 32,33: replicated bf16(-enorm/32)
            const ushort_t ev = f2bf(s * -0.03125f);
            ushort_t eo[8];
#pragma unroll
            for (int j = 0; j < 8; ++j) eo[j] = ev;
            *(bf16x8*)(Bg + ((size_t)(32 + g) * K_CODES + k) * 8) = *(bf16x8*)eo;
        }
        if (gi == 0) { ctrl->done = 0u; ctrl->lsum = 0ull; }
    }
}

// ---------------- K2: main (R11 loop/epilogue verbatim; staged-As prologue) ----------------
// LDS map (bytes):
//   As   [     0, 32768)  [32 planes][64 rows][8] bf16
//   Bs   [ 32768,131072)  3 x 32768 ring
//   et   [ 32768, 99328)  [64][260] f32 (epilogue, alias Bs)
//   pmin [131072,133120)  [64][4] u64
//   znL  [133120,133376)  [64] f32
//   idxL [133376,133632)  [64] i32
__global__ __launch_bounds__(512, 2) void vq_main(
        const float* __restrict__ emb, const ushort_t* __restrict__ Ag,
        const float* __restrict__ znG, const ushort_t* __restrict__ Bg,
        float* __restrict__ out, float* __restrict__ loss, Ctrl* __restrict__ ctrl) {
    __shared__ __align__(16) char smem[133632];
    ushort_t* As  = (ushort_t*)smem;
    ushort_t* Bs  = (ushort_t*)(smem + 32768);
    float*    et  = (float*)(smem + 32768);
    u64*      pmin = (u64*)(smem + 131072);
    float*    znL = (float*)(smem + 133120);
    int*      idxL = (int*)(smem + 133376);

    const int bid = blockIdx.x, tid = threadIdx.x;
    const int b = bid >> 4;
    const int hw0 = (bid & 15) * 64;
    const int w = tid >> 6, l = tid & 63;
    const int wm = w >> 2, wn = w & 3;               // 2 row-groups x 4 code-groups
    const int lane31 = l & 31, hi = l >> 5;

    auto stage = [&](int sbuf, int t) {
#pragma unroll
        for (int qq = 0; qq < 4; ++qq) {
            int g = qq * 512 + tid;                  // [0,2048) granules
            int lp = g >> 10, kk = g & 1023;
            gload_lds16(Bg + ((size_t)(t * 2 + lp) * K_CODES + kk) * 8,
                        Bs + (size_t)sbuf * 16384 + (size_t)g * 8);
        }
    };

    // ---- prologue: stage B chunks 0,1 + As + znL; ONE barrier ----
    stage(0, 0);
    stage(1, 1);
    {
        // As: 1024 granules of 16B; wave-uniform plane, lane-consecutive rows
#pragma unroll
        for (int qq = 0; qq < 2; ++qq) {
            int j = qq * 512 + tid;                  // g = j>>6 (uniform/wave), r = j&63
            gload_lds16(Ag + ((size_t)(j >> 6) * N_VEC + bid * 64 + (j & 63)) * 8,
                        As + (size_t)j * 8);
        }
        if (tid < 64) znL[tid] = znG[bid * 64 + tid];
    }
    __syncthreads();                                 // drains all stages; znL visible

    // ---- K loop: 17 chunks (last = enorm), 3-buffer counted-vmcnt pipeline ----
    f32x16 acc[8];
#pragma unroll
    for (int cf = 0; cf < 8; ++cf)
#pragma unroll
        for (int r = 0; r < 16; ++r) acc[cf][r] = 0.f;

#define COMPUTE(BUF, T, ONES) do {                                              \
        const ushort_t* Bp = Bs + (size_t)(BUF) * 16384 +                       \
                             ((size_t)hi * 1024 + wn * 256) * 8;                \
        bf16x8 a;                                                               \
        if (ONES) { _Pragma("unroll")                                           \
            for (int j = 0; j < 8; ++j) a[j] = (short)0x3F80;                   \
        } else {                                                                \
            a = *(const bf16x8*)(As + ((size_t)((T) * 2 + hi) * 64              \
                                       + wm * 32 + lane31) * 8);                \
        }                                                                       \
        __builtin_amdgcn_s_setprio(1);                                          \
        _Pragma("unroll")                                                       \
        for (int cf = 0; cf < 8; ++cf) {                                        \
            const bf16x8 bf = *(const bf16x8*)(Bp + (size_t)(cf * 32 + lane31) * 8); \
            acc[cf] = __builtin_amdgcn_mfma_f32_32x32x16_bf16(bf, a, acc[cf], 0, 0, 0); \
        }                                                                       \
        __builtin_amdgcn_s_setprio(0);                                          \
    } while (0)

    int bcur = 0, bnxt = 2;
    for (int t = 0; t < 15; ++t) {
        stage(bnxt, t + 2);                          // slot (t+2)%3: last read iter t-1
        asm volatile("s_waitcnt vmcnt(8)" ::: "memory");   // chunk t done; t+1,t+2 fly
        __builtin_amdgcn_s_barrier();
        __builtin_amdgcn_sched_barrier(0);
        COMPUTE(bcur, t, false);
        __builtin_amdgcn_s_barrier();                // all reads of chunk t done
        bcur = (bcur == 2) ? 0 : bcur + 1;
        bnxt = (bnxt == 2) ? 0 : bnxt + 1;
    }
    asm volatile("s_waitcnt vmcnt(4)" ::: "memory");
    __builtin_amdgcn_s_barrier();
    __builtin_amdgcn_sched_barrier(0);
    COMPUTE(bcur, 15, false);
    __builtin_amdgcn_s_barrier();
    bcur = (bcur == 2) ? 0 : bcur + 1;
    asm volatile("s_waitcnt vmcnt(0)" ::: "memory");
    __builtin_amdgcn_s_barrier();
    __builtin_amdgcn_sched_barrier(0);
    COMPUTE(bcur, 16, true);                         // enorm chunk: A = ones
#undef COMPUTE

    // ---- epilogue: lane-local argmax over 128 codes (acc = z.e - enorm/2) ----
    {
        float m = acc[0][0];
#pragma unroll
        for (int cf = 0; cf < 8; ++cf)
#pragma unroll
            for (int r = 0; r < 16; ++r) m = fmaxf(m, acc[cf][r]);
        unsigned cc = 0xffffffffu;
#pragma unroll
        for (int cf = 0; cf < 8; ++cf)
#pragma unroll
            for (int r = 0; r < 16; ++r) {
                const unsigned cst = (unsigned)(cf * 32 + (r & 3) + 8 * (r >> 2));
                if (acc[cf][r] == m) cc = cst < cc ? cst : cc;
            }
        unsigned code = cc + (unsigned)(wn * 256 + 4 * hi);
        const float om = __shfl_xor(m, 32);
        const unsigned oc = __shfl_xor(code, 32);
        if (om > m || (om == m && oc < code)) { m = om; code = oc; }
        unsigned sb = __float_as_uint(m);
        unsigned s = sb ^ (unsigned)(((int)sb >> 31) | 0x80000000);
        u64 key = ((u64)(~s) << 32) | code;          // min key = max score, tie->min code
        if (l < 32) pmin[(wm * 32 + lane31) * 4 + wn] = key;
    }
    __syncthreads();

    // ---- final per-row min across 4 code-waves -> idx + loss ----
    if (tid < 64) {
        u64 b0 = pmin[tid * 4], b1 = pmin[tid * 4 + 1];
        u64 b2 = pmin[tid * 4 + 2], b3 = pmin[tid * 4 + 3];
        u64 m01 = b0 < b1 ? b0 : b1;
        u64 m23 = b2 < b3 ? b2 : b3;
        u64 best = m01 < m23 ? m01 : m23;
        idxL[tid] = (int)(best & 1023u);
        unsigned us = ~(unsigned)(best >> 32);
        unsigned fb = (us & 0x80000000u) ? (us ^ 0x80000000u) : ~us;
        float sc = __uint_as_float(fb);              // max(z.e - enorm/2)
        float lp = znL[tid] - 2.0f * sc;             // ||z||^2 + enorm - 2 z.e
#pragma unroll
        for (int off = 32; off >= 1; off >>= 1) lp += __shfl_xor(lp, off);
        if (tid == 0) {
            u64 fix = (u64)(long long)((double)lp * 1048576.0);
            atomicAdd(&ctrl->lsum, fix);
            __threadfence();
            unsigned old = atomicAdd(&ctrl->done, 1u);
            if (old == (NBLK - 1)) {
                __threadfence();
                u64 tot = atomicAdd(&ctrl->lsum, 0ull);
                loss[0] = (float)((double)tot * (1.25 / (1048576.0 * 4194304.0)));
            }
        }
    }
    __syncthreads();   // idxL ready; Bs dead -> et may overwrite

    // ---- gather emb rows -> et[local row] (1 KB coalesced per wave pass) ----
#pragma unroll
    for (int jj = 0; jj < 8; ++jj) {
        int j = jj * 512 + tid;                      // row = j>>6 in [0,64), gr = j&63
        int mrow = j >> 6, gr = j & 63;
        float4 v = *(const float4*)(emb + (size_t)idxL[mrow] * D_DIM + gr * 4);
        *(float4*)(et + mrow * 260 + gr * 4) = v;
    }
    __syncthreads();

    // ---- out[b][d][hw0+hw] = et[hw][d] ----
    const int hw4 = (tid & 15) * 4;
    const int dr = tid >> 4;                         // 0..31
#pragma unroll
    for (int it = 0; it < 8; ++it) {
        const int d = it * 32 + dr;
        float4 qv;
        qv.x = et[(hw4 + 0) * 260 + d];
        qv.y = et[(hw4 + 1) * 260 + d];
        qv.z = et[(hw4 + 2) * 260 + d];
        qv.w = et[(hw4 + 3) * 260 + d];
        *(float4*)(out + ((size_t)(b * 256 + d)) * 1024 + hw0 + hw4) = qv;
    }
}

extern "C" void kernel_launch(void* const* d_in, const int* in_sizes, int n_in,
                              void* d_out, int out_size, void* d_ws, size_t ws_size,
                              hipStream_t stream) {
    const float* z   = (const float*)d_in[0];
    const float* emb = (const float*)d_in[1];
    float* out  = (float*)d_out;
    float* loss = out + ZQ_SIZE;

    char* ws = (char*)d_ws;
    ushort_t* Ag = (ushort_t*)(ws);             // 8,388,608 B  [32][16384] granules
    ushort_t* Bg = (ushort_t*)(ws + 8388608);   //   557,056 B  [34][1024] granules
    float* znG   = (float*)(ws + 8945664);      //    65,536 B
    Ctrl* ctrl   = (Ctrl*)(ws + 9011200);       //        16 B

    vq_prep<<<320, 512, 0, stream>>>(z, emb, Ag, znG, Bg, ctrl);
    vq_main<<<NBLK, 512, 0, stream>>>(emb, Ag, znG, Bg, out, loss, ctrl);
}